// Round 1
// baseline (257.128 us; speedup 1.0000x reference)
//
#include <hip/hip_runtime.h>
#include <math.h>

#define N_HW 12544
#define JCH 14
#define TILE_N 128
#define TPC 7                    // tiles per chunk; 14*7*128 = 12544
#define CHUNK (TILE_N*TPC)       // 896
#define XTS 36                   // transposed-tile LDS stride (16B-aligned rows, bank-rotated)

// ws layout in floats
#define WS_PQ (64*JCH*1024)          // partial S: 917504 floats
#define WS_U  (WS_PQ + 64*JCH*96)    // partial Q: 86016 floats; U: 64*128 floats

// ---------------- Kernel 1: per-(batch,chunk) partial S = X X^T and Q0 = X P ----------------
__global__ __launch_bounds__(256)
void k1_partial(const float* __restrict__ x, const float* __restrict__ p,
                float* __restrict__ pS, float* __restrict__ pQ)
{
    const int b = blockIdx.y, j = blockIdx.x;
    const int tid  = threadIdx.x;
    const int lane = tid & 63, wave = tid >> 6;
    const int ty = lane >> 3, tx = lane & 7;

    __shared__ float XsT[TILE_N][XTS];   // transposed X tile: [n][c]
    __shared__ float Ps[TILE_N*3];
    __shared__ float redS[4][64][17];    // stride 17: odd -> conflict-free lane writes
    __shared__ float redQ[192];

    const float* Xb = x + (size_t)b * 32 * N_HW;
    const float* Pb = p + (size_t)b * N_HW * 3;

    float accS[4][4] = {};
    float accQ = 0.f;
    // Q0 task map for tid<192: (c, r, half)
    const int qc = tid / 6, qrh = tid % 6;
    const int qr = qrh >> 1, qh = qrh & 1;
    const int c_ld = tid >> 3, q_ld = tid & 7;

    for (int t = 0; t < TPC; ++t) {
        const int nbase = j * CHUNK + t * TILE_N;
        __syncthreads();
        // stage X tile transposed into LDS (coalesced float4 row reads)
        {
            const float* row = Xb + (size_t)c_ld * N_HW + nbase;
            #pragma unroll
            for (int k = 0; k < 4; ++k) {
                const int nn = 4 * (q_ld + 8 * k);
                float4 v = *(const float4*)(row + nn);
                XsT[nn+0][c_ld] = v.x; XsT[nn+1][c_ld] = v.y;
                XsT[nn+2][c_ld] = v.z; XsT[nn+3][c_ld] = v.w;
            }
        }
        // stage P tile (384 contiguous floats)
        for (int i = tid; i < TILE_N*3; i += 256)
            Ps[i] = Pb[(size_t)nbase * 3 + i];
        __syncthreads();

        // S partial: each wave handles 32 of the 128 n's, 4x4 register tile per lane
        #pragma unroll 8
        for (int k = 0; k < 32; ++k) {
            const int n = wave * 32 + k;
            float4 a  = *(const float4*)&XsT[n][4*ty];
            float4 bb = *(const float4*)&XsT[n][4*tx];
            accS[0][0] += a.x*bb.x; accS[0][1] += a.x*bb.y; accS[0][2] += a.x*bb.z; accS[0][3] += a.x*bb.w;
            accS[1][0] += a.y*bb.x; accS[1][1] += a.y*bb.y; accS[1][2] += a.y*bb.z; accS[1][3] += a.y*bb.w;
            accS[2][0] += a.z*bb.x; accS[2][1] += a.z*bb.y; accS[2][2] += a.z*bb.z; accS[2][3] += a.z*bb.w;
            accS[3][0] += a.w*bb.x; accS[3][1] += a.w*bb.y; accS[3][2] += a.w*bb.z; accS[3][3] += a.w*bb.w;
        }
        // Q0 partial: 192 tasks (c in 32, r in 3, half in 2), 64 n each
        if (tid < 192) {
            const int n0 = qh * 64;
            #pragma unroll 8
            for (int k = 0; k < 64; ++k) {
                const int n = n0 + k;
                accQ += XsT[n][qc] * Ps[3*n + qr];
            }
        }
    }

    __syncthreads();
    #pragma unroll
    for (int i = 0; i < 4; ++i)
        #pragma unroll
        for (int k = 0; k < 4; ++k)
            redS[wave][lane][i*4+k] = accS[i][k];
    if (tid < 192) redQ[tid] = accQ;
    __syncthreads();

    // cross-wave reduce + write partials (coalesced)
    float* pSb = pS + ((size_t)b * JCH + j) * 1024;
    #pragma unroll
    for (int i = 0; i < 4; ++i) {
        const int e = tid + 256 * i;
        const int r = e >> 5, c = e & 31;
        const int ln  = (r >> 2) * 8 + (c >> 2);
        const int idx = (r & 3) * 4 + (c & 3);
        pSb[e] = redS[0][ln][idx] + redS[1][ln][idx] + redS[2][ln][idx] + redS[3][ln][idx];
    }
    if (tid < 96) {
        const int c = tid / 3, r = tid % 3;
        pQ[((size_t)b * JCH + j) * 96 + tid] = redQ[c*6 + r*2] + redQ[c*6 + r*2 + 1];
    }
}

// ---------------- Kernel 2: per-batch V = S*Q0, CholQR2 -> U (32x3, padded to 32x4) ----------------
__global__ __launch_bounds__(128)
void k2_solve(const float* __restrict__ pS, const float* __restrict__ pQ,
              float* __restrict__ Uo)
{
    const int b = blockIdx.x, tid = threadIdx.x;
    __shared__ float S[1024];
    __shared__ float Qv[96];
    __shared__ float V[96];
    __shared__ float G[6], L[6];

    #pragma unroll
    for (int i = 0; i < 8; ++i) {
        const int e = tid + 128 * i;
        float s = 0.f;
        for (int jj = 0; jj < JCH; ++jj) s += pS[((size_t)b*JCH + jj)*1024 + e];
        S[e] = s;
    }
    if (tid < 96) {
        float s = 0.f;
        for (int jj = 0; jj < JCH; ++jj) s += pQ[((size_t)b*JCH + jj)*96 + tid];
        Qv[tid] = s;
    }
    __syncthreads();
    if (tid < 96) {
        const int c = tid / 3, r = tid % 3;
        float s = 0.f;
        #pragma unroll 8
        for (int cc = 0; cc < 32; ++cc) s += S[c*32 + cc] * Qv[cc*3 + r];
        V[tid] = s;
    }
    for (int round = 0; round < 2; ++round) {
        __syncthreads();
        if (tid < 6) {
            // (r,s) pairs of lower-tri Gram: tid -> r = level, s = offset
            const int r = (tid > 2) ? 2 : ((tid > 0) ? 1 : 0);
            const int s = tid - (r * (r + 1)) / 2;
            float g = 0.f;
            for (int c = 0; c < 32; ++c) g += V[c*3 + r] * V[c*3 + s];
            G[tid] = g;
        }
        __syncthreads();
        if (tid == 0) {
            const float l00 = sqrtf(G[0]);
            const float l10 = G[1] / l00, l20 = G[3] / l00;
            const float l11 = sqrtf(G[2] - l10*l10);
            const float l21 = (G[4] - l20*l10) / l11;
            const float l22 = sqrtf(G[5] - l20*l20 - l21*l21);
            L[0]=l00; L[1]=l10; L[2]=l11; L[3]=l20; L[4]=l21; L[5]=l22;
        }
        __syncthreads();
        if (tid < 32) {
            const float v0 = V[tid*3+0], v1 = V[tid*3+1], v2 = V[tid*3+2];
            const float u0 = v0 / L[0];
            const float u1 = (v1 - L[1]*u0) / L[2];
            const float u2 = (v2 - L[3]*u0 - L[4]*u1) / L[5];
            V[tid*3+0] = u0; V[tid*3+1] = u1; V[tid*3+2] = u2;
        }
    }
    __syncthreads();
    if (tid < 32) {
        Uo[(size_t)b*128 + tid*4 + 0] = V[tid*3+0];
        Uo[(size_t)b*128 + tid*4 + 1] = V[tid*3+1];
        Uo[(size_t)b*128 + tid*4 + 2] = V[tid*3+2];
        Uo[(size_t)b*128 + tid*4 + 3] = 0.f;
    }
}

// ---------------- Kernel 3: out = U * (U^T X), pure streaming ----------------
__global__ __launch_bounds__(256)
void k3_out(const float* __restrict__ x, const float* __restrict__ Uw,
            float* __restrict__ out)
{
    const int b = blockIdx.y, tid = threadIdx.x;
    __shared__ float Us[32][4];
    if (tid < 128) ((float*)Us)[tid] = Uw[(size_t)b*128 + tid];
    __syncthreads();
    const int g = blockIdx.x * 256 + tid;
    if (g >= N_HW/4) return;

    const float* Xb = x   + (size_t)b * 32 * N_HW + 4*(size_t)g;
    float*       Ob = out + (size_t)b * 32 * N_HW + 4*(size_t)g;

    float t0x=0,t0y=0,t0z=0,t0w=0;
    float t1x=0,t1y=0,t1z=0,t1w=0;
    float t2x=0,t2y=0,t2z=0,t2w=0;
    #pragma unroll 8
    for (int c = 0; c < 32; ++c) {
        float4 xv = *(const float4*)(Xb + (size_t)c * N_HW);
        const float u0 = Us[c][0], u1 = Us[c][1], u2 = Us[c][2];
        t0x += u0*xv.x; t0y += u0*xv.y; t0z += u0*xv.z; t0w += u0*xv.w;
        t1x += u1*xv.x; t1y += u1*xv.y; t1z += u1*xv.z; t1w += u1*xv.w;
        t2x += u2*xv.x; t2y += u2*xv.y; t2z += u2*xv.z; t2w += u2*xv.w;
    }
    #pragma unroll 8
    for (int c = 0; c < 32; ++c) {
        const float u0 = Us[c][0], u1 = Us[c][1], u2 = Us[c][2];
        float4 o;
        o.x = u0*t0x + u1*t1x + u2*t2x;
        o.y = u0*t0y + u1*t1y + u2*t2y;
        o.z = u0*t0z + u1*t1z + u2*t2z;
        o.w = u0*t0w + u1*t1w + u2*t2w;
        *(float4*)(Ob + (size_t)c * N_HW) = o;
    }
}

extern "C" void kernel_launch(void* const* d_in, const int* in_sizes, int n_in,
                              void* d_out, int out_size, void* d_ws, size_t ws_size,
                              hipStream_t stream)
{
    const float* x = (const float*)d_in[0];
    const float* p = (const float*)d_in[1];
    float* ws = (float*)d_ws;
    float* pS = ws;            // 64*14*1024 floats
    float* pQ = ws + WS_PQ;    // 64*14*96 floats
    float* U  = ws + WS_U;     // 64*128 floats
    float* out = (float*)d_out;

    hipLaunchKernelGGL(k1_partial, dim3(JCH, 64), dim3(256), 0, stream, x, p, pS, pQ);
    hipLaunchKernelGGL(k2_solve,   dim3(64),      dim3(128), 0, stream, pS, pQ, U);
    hipLaunchKernelGGL(k3_out,     dim3((N_HW/4 + 255)/256, 64), dim3(256), 0, stream, x, U, out);
}

// Round 2
// 254.013 us; speedup vs baseline: 1.0123x; 1.0123x over previous
//
#include <hip/hip_runtime.h>
#include <math.h>

#define N_HW 12544
#define TN 256              // n per block
#define NCHUNK 49           // 49 * 256 = 12544

// ws layout (floats): Sg[64][1024], Qg[64][96], U[64][128]
#define WS_QG 65536
#define WS_U  (WS_QG + 64*96)
#define ZTOT  (WS_U)        // floats to zero (S + Q)

// XOR-swizzled quad index into dense 32x256 tile (64 quads/row).
// key = 2*(row>>3): makes the 8-row b128 read patterns conflict-free.
__device__ __forceinline__ int XQ(int c, int q) {
    return (c << 6) + ((q & ~7) | ((q ^ ((c >> 3) << 1)) & 7));
}

// ---------------- k0: zero the S/Q accumulators ----------------
__global__ __launch_bounds__(256)
void k0_zero(float* __restrict__ ws)
{
    const int g = blockIdx.x * 256 + threadIdx.x;   // float4 index
    if (g < ZTOT / 4) ((float4*)ws)[g] = make_float4(0.f, 0.f, 0.f, 0.f);
}

// ---------------- k1: per-(batch,chunk) S += X X^T, Q += X P (atomic) ----------------
__global__ __launch_bounds__(256)
void k1_gram(const float* __restrict__ x, const float* __restrict__ p,
             float* __restrict__ Sg, float* __restrict__ Qg)
{
    const int b = blockIdx.y, j = blockIdx.x;
    const int tid  = threadIdx.x;
    const int lane = tid & 63, wave = tid >> 6;
    const int nbase = j * TN;

    __shared__ float4 Xs4[32 * 64];            // 32 KB, swizzled; reused as reduce scratch
    __shared__ alignas(16) float Ps[TN * 3];   // P tile [n][r], 3 KB
    __shared__ float Qred[8 * 32 * 3];         // 3 KB

    // ---- stage X tile (row-major, swizzled) ----
    {
        const int c = tid >> 3, q0 = tid & 7;
        const float4* xrow = (const float4*)(x + ((size_t)b * 32 + c) * N_HW + nbase);
        #pragma unroll
        for (int k = 0; k < 8; ++k) {
            const int q = q0 + 8 * k;
            Xs4[XQ(c, q)] = xrow[q];
        }
    }
    // ---- stage P tile (768 contiguous floats) ----
    {
        const float* pb = p + (size_t)b * N_HW * 3 + (size_t)nbase * 3;
        #pragma unroll
        for (int i = 0; i < 3; ++i) Ps[tid + 256 * i] = pb[tid + 256 * i];
    }
    __syncthreads();

    // ---- S-loop: 8x4 register tile per lane, waves split n ----
    const int sub = lane >> 5, ry = (lane >> 3) & 3, cx = lane & 7;
    const int qbase = wave * 16;
    float acc[8][4] = {};
    for (int t = 0; t < 8; ++t) {
        const int q = qbase + 2 * t + sub;
        float4 bq[4], a[8];
        #pragma unroll
        for (int j2 = 0; j2 < 4; ++j2) bq[j2] = Xs4[XQ(4 * cx + j2, q)];
        #pragma unroll
        for (int i = 0; i < 8; ++i)   a[i]  = Xs4[XQ(8 * ry + i, q)];
        #pragma unroll
        for (int i = 0; i < 8; ++i)
            #pragma unroll
            for (int j2 = 0; j2 < 4; ++j2)
                acc[i][j2] += a[i].x * bq[j2].x + a[i].y * bq[j2].y
                            + a[i].z * bq[j2].z + a[i].w * bq[j2].w;
    }

    // ---- Q-pass: thread (c,g) covers 32 n, vectorized P reads ----
    {
        const int qc = tid & 31, g = tid >> 5;
        float q0a = 0.f, q1a = 0.f, q2a = 0.f;
        const float4* Ps4 = (const float4*)Ps;
        #pragma unroll
        for (int t = 0; t < 8; ++t) {
            const int q = g * 8 + t;
            float4 xv = Xs4[XQ(qc, q)];
            float4 p0 = Ps4[3 * q], p1 = Ps4[3 * q + 1], p2 = Ps4[3 * q + 2];
            // Ps layout [n][r]: p0 = {n0r0 n0r1 n0r2 n1r0}, p1 = {n1r1 n1r2 n2r0 n2r1}, p2 = {n2r2 n3r0 n3r1 n3r2}
            q0a += xv.x * p0.x + xv.y * p0.w + xv.z * p1.z + xv.w * p2.y;
            q1a += xv.x * p0.y + xv.y * p1.x + xv.z * p1.w + xv.w * p2.z;
            q2a += xv.x * p0.z + xv.y * p1.y + xv.z * p2.x + xv.w * p2.w;
        }
        Qred[g * 96 + qc * 3 + 0] = q0a;
        Qred[g * 96 + qc * 3 + 1] = q1a;
        Qred[g * 96 + qc * 3 + 2] = q2a;
    }

    __syncthreads();
    // ---- dump acc into reused Xs4, then reduce across waves/subs ----
    #pragma unroll
    for (int i = 0; i < 8; ++i)
        Xs4[tid * 8 + i] = make_float4(acc[i][0], acc[i][1], acc[i][2], acc[i][3]);
    __syncthreads();

    const float* red = (const float*)Xs4;
    float* Sb = Sg + (size_t)b * 1024;
    #pragma unroll
    for (int it = 0; it < 4; ++it) {
        const int e = tid + 256 * it;
        const int r = e >> 5, cl = e & 31;
        const int ery = r >> 3, ei = r & 7, ecx = cl >> 2, ej = cl & 3;
        const int slot = ery * 8 + ecx;
        float s = 0.f;
        #pragma unroll
        for (int w = 0; w < 4; ++w) {
            s += red[(w * 64 +      slot) * 32 + ei * 4 + ej];
            s += red[(w * 64 + 32 + slot) * 32 + ei * 4 + ej];
        }
        atomicAdd(&Sb[e], s);
    }
    if (tid < 96) {
        float s = 0.f;
        #pragma unroll
        for (int g = 0; g < 8; ++g) s += Qred[g * 96 + tid];
        atomicAdd(&Qg[(size_t)b * 96 + tid], s);
    }
}

// ---------------- k2: per-batch V = S*Q0, CholQR2 -> U (32x3, padded to 32x4) ----------------
__global__ __launch_bounds__(128)
void k2_solve(const float* __restrict__ Sg, const float* __restrict__ Qg,
              float* __restrict__ Uo)
{
    const int b = blockIdx.x, tid = threadIdx.x;
    __shared__ float S[1024];
    __shared__ float Qv[96];
    __shared__ float V[96];
    __shared__ float G[6], L[6];

    #pragma unroll
    for (int i = 0; i < 8; ++i) S[tid + 128 * i] = Sg[(size_t)b * 1024 + tid + 128 * i];
    if (tid < 96) Qv[tid] = Qg[(size_t)b * 96 + tid];
    __syncthreads();
    if (tid < 96) {
        const int c = tid / 3, r = tid % 3;
        float s = 0.f;
        #pragma unroll 8
        for (int cc = 0; cc < 32; ++cc) s += S[c * 32 + cc] * Qv[cc * 3 + r];
        V[tid] = s;
    }
    for (int round = 0; round < 2; ++round) {
        __syncthreads();
        if (tid < 6) {
            const int r = (tid > 2) ? 2 : ((tid > 0) ? 1 : 0);
            const int s = tid - (r * (r + 1)) / 2;
            float g = 0.f;
            for (int c = 0; c < 32; ++c) g += V[c * 3 + r] * V[c * 3 + s];
            G[tid] = g;
        }
        __syncthreads();
        if (tid == 0) {
            const float l00 = sqrtf(G[0]);
            const float l10 = G[1] / l00, l20 = G[3] / l00;
            const float l11 = sqrtf(G[2] - l10 * l10);
            const float l21 = (G[4] - l20 * l10) / l11;
            const float l22 = sqrtf(G[5] - l20 * l20 - l21 * l21);
            L[0] = l00; L[1] = l10; L[2] = l11; L[3] = l20; L[4] = l21; L[5] = l22;
        }
        __syncthreads();
        if (tid < 32) {
            const float v0 = V[tid * 3 + 0], v1 = V[tid * 3 + 1], v2 = V[tid * 3 + 2];
            const float u0 = v0 / L[0];
            const float u1 = (v1 - L[1] * u0) / L[2];
            const float u2 = (v2 - L[3] * u0 - L[4] * u1) / L[5];
            V[tid * 3 + 0] = u0; V[tid * 3 + 1] = u1; V[tid * 3 + 2] = u2;
        }
    }
    __syncthreads();
    if (tid < 32) {
        Uo[(size_t)b * 128 + tid * 4 + 0] = V[tid * 3 + 0];
        Uo[(size_t)b * 128 + tid * 4 + 1] = V[tid * 3 + 1];
        Uo[(size_t)b * 128 + tid * 4 + 2] = V[tid * 3 + 2];
        Uo[(size_t)b * 128 + tid * 4 + 3] = 0.f;
    }
}

// ---------------- k3: out = U * (U^T X), pure streaming ----------------
__global__ __launch_bounds__(256)
void k3_out(const float* __restrict__ x, const float* __restrict__ Uw,
            float* __restrict__ out)
{
    const int b = blockIdx.y, tid = threadIdx.x;
    __shared__ float Us[32][4];
    if (tid < 128) ((float*)Us)[tid] = Uw[(size_t)b * 128 + tid];
    __syncthreads();
    const int g = blockIdx.x * 256 + tid;
    if (g >= N_HW / 4) return;

    const float* Xb = x   + (size_t)b * 32 * N_HW + 4 * (size_t)g;
    float*       Ob = out + (size_t)b * 32 * N_HW + 4 * (size_t)g;

    float t0x = 0, t0y = 0, t0z = 0, t0w = 0;
    float t1x = 0, t1y = 0, t1z = 0, t1w = 0;
    float t2x = 0, t2y = 0, t2z = 0, t2w = 0;
    #pragma unroll 8
    for (int c = 0; c < 32; ++c) {
        float4 xv = *(const float4*)(Xb + (size_t)c * N_HW);
        const float u0 = Us[c][0], u1 = Us[c][1], u2 = Us[c][2];
        t0x += u0 * xv.x; t0y += u0 * xv.y; t0z += u0 * xv.z; t0w += u0 * xv.w;
        t1x += u1 * xv.x; t1y += u1 * xv.y; t1z += u1 * xv.z; t1w += u1 * xv.w;
        t2x += u2 * xv.x; t2y += u2 * xv.y; t2z += u2 * xv.z; t2w += u2 * xv.w;
    }
    #pragma unroll 8
    for (int c = 0; c < 32; ++c) {
        const float u0 = Us[c][0], u1 = Us[c][1], u2 = Us[c][2];
        float4 o;
        o.x = u0 * t0x + u1 * t1x + u2 * t2x;
        o.y = u0 * t0y + u1 * t1y + u2 * t2y;
        o.z = u0 * t0z + u1 * t1z + u2 * t2z;
        o.w = u0 * t0w + u1 * t1w + u2 * t2w;
        *(float4*)(Ob + (size_t)c * N_HW) = o;
    }
}

extern "C" void kernel_launch(void* const* d_in, const int* in_sizes, int n_in,
                              void* d_out, int out_size, void* d_ws, size_t ws_size,
                              hipStream_t stream)
{
    const float* x = (const float*)d_in[0];
    const float* p = (const float*)d_in[1];
    float* ws = (float*)d_ws;
    float* Sg = ws;
    float* Qg = ws + WS_QG;
    float* U  = ws + WS_U;
    float* out = (float*)d_out;

    hipLaunchKernelGGL(k0_zero, dim3((ZTOT / 4 + 255) / 256), dim3(256), 0, stream, ws);
    hipLaunchKernelGGL(k1_gram, dim3(NCHUNK, 64), dim3(256), 0, stream, x, p, Sg, Qg);
    hipLaunchKernelGGL(k2_solve, dim3(64), dim3(128), 0, stream, Sg, Qg, U);
    hipLaunchKernelGGL(k3_out, dim3((N_HW / 4 + 255) / 256, 64), dim3(256), 0, stream, x, U, out);
}

// Round 4
// 250.267 us; speedup vs baseline: 1.0274x; 1.0150x over previous
//
#include <hip/hip_runtime.h>
#include <math.h>

#define N_HW 12544
#define TN 128               // n per block tile
#define NCH 98               // 98 * 128 = 12544

// ws layout (floats): Sg[64][1024], Qg[64][96], U[64][128]
#define WS_QG 65536
#define WS_U  (WS_QG + 64*96)
#define ZTOT  (WS_U)         // floats to zero (S + Q)

typedef __attribute__((ext_vector_type(8)))  short short8;
typedef __attribute__((ext_vector_type(16))) float f32x16;
typedef __attribute__((ext_vector_type(4)))  float f32x4;

#define MFMA(a, b, c) __builtin_amdgcn_mfma_f32_32x32x16_bf16((a), (b), (c), 0, 0, 0)

// Exact 3-way truncating split: f == H + M + L (24 mantissa bits total).
__device__ __forceinline__ void split3(float f, ushort& h, ushort& m, ushort& l) {
    unsigned u = __builtin_bit_cast(unsigned, f);
    h = (ushort)(u >> 16);
    float fh = __builtin_bit_cast(float, u & 0xffff0000u);
    float rm = f - fh;                                   // exact
    unsigned um = __builtin_bit_cast(unsigned, rm);
    m = (ushort)(um >> 16);
    float fm = __builtin_bit_cast(float, um & 0xffff0000u);
    float rl = rm - fm;                                  // exact, <= 8 sig bits
    l = (ushort)(__builtin_bit_cast(unsigned, rl) >> 16);
}

// XOR-swizzled octet slot in a 32-row x 16-octet bf16 tile.
__device__ __forceinline__ int xq(int c, int o) {
    return c * 16 + ((o & 8) | ((o ^ c) & 7));
}

// ---------------- k0: zero the S/Q accumulators ----------------
__global__ __launch_bounds__(256)
void k0_zero(float* __restrict__ ws)
{
    const int g = blockIdx.x * 256 + threadIdx.x;
    if (g < ZTOT / 4) ((float4*)ws)[g] = make_float4(0.f, 0.f, 0.f, 0.f);
}

// ---------------- k1: MFMA Gram  S += X X^T,  Q += X P  (split-bf16, exact to ~2^-24) ----------------
__global__ __launch_bounds__(256)
void k1_gram(const float* __restrict__ x, const float* __restrict__ p,
             float* __restrict__ Sg, float* __restrict__ Qg)
{
    const int b = blockIdx.y, j = blockIdx.x;
    const int tid = threadIdx.x;
    const int lane = tid & 63, wave = tid >> 6;
    const int nbase = j * TN;

    __shared__ uint4 XS[3 * 512];                         // H/M/L tiles, 24 KB (reused as reduce scratch)
    __shared__ alignas(16) ushort PTH[3 * TN], PTM[3 * TN], PTL[3 * TN];  // P^T tiles [r][n]
    __shared__ float Ssum[1024], T2[1024], T3[1024];      // 12 KB
    float* dmp = (float*)XS;

    // ---- stage X tile: global float4 -> 3-way split -> swizzled bf16 octets ----
    {
        const int c = tid >> 3, oc = tid & 7;
        const float4* xr = (const float4*)(x + ((size_t)b * 32 + c) * N_HW + nbase);
        #pragma unroll
        for (int t = 0; t < 2; ++t) {
            const int o = oc + 8 * t;
            float4 f0 = xr[2 * o], f1 = xr[2 * o + 1];
            float fv[8] = {f0.x, f0.y, f0.z, f0.w, f1.x, f1.y, f1.z, f1.w};
            unsigned hw[4], mw[4], lw[4];
            #pragma unroll
            for (int i = 0; i < 4; ++i) {
                ushort h0, m0, l0, h1, m1, l1;
                split3(fv[2 * i],     h0, m0, l0);
                split3(fv[2 * i + 1], h1, m1, l1);
                hw[i] = (unsigned)h0 | ((unsigned)h1 << 16);
                mw[i] = (unsigned)m0 | ((unsigned)m1 << 16);
                lw[i] = (unsigned)l0 | ((unsigned)l1 << 16);
            }
            const int s = xq(c, o);
            XS[s]        = make_uint4(hw[0], hw[1], hw[2], hw[3]);
            XS[512 + s]  = make_uint4(mw[0], mw[1], mw[2], mw[3]);
            XS[1024 + s] = make_uint4(lw[0], lw[1], lw[2], lw[3]);
        }
    }
    // ---- stage P^T tile ----
    if (tid < TN) {
        const float* pb = p + (size_t)b * N_HW * 3 + (size_t)(nbase + tid) * 3;
        #pragma unroll
        for (int r = 0; r < 3; ++r) {
            ushort h, m, l;
            split3(pb[r], h, m, l);
            PTH[r * TN + tid] = h; PTM[r * TN + tid] = m; PTL[r * TN + tid] = l;
        }
    }
    __syncthreads();

    // ---- MFMA K-loop: waves split the 8 K-steps ----
    f32x16 D1 = {0,0,0,0,0,0,0,0,0,0,0,0,0,0,0,0};
    f32x16 D2 = {0,0,0,0,0,0,0,0,0,0,0,0,0,0,0,0};
    f32x16 D3 = {0,0,0,0,0,0,0,0,0,0,0,0,0,0,0,0};
    f32x16 DQ = {0,0,0,0,0,0,0,0,0,0,0,0,0,0,0,0};
    const int cl = lane & 31, g = lane >> 5;
    const int rr = (cl < 3) ? cl : 0;
    for (int s = wave; s < 8; s += 4) {
        const int sl = xq(cl, 2 * s + g);
        short8 xh = __builtin_bit_cast(short8, XS[sl]);
        short8 xm = __builtin_bit_cast(short8, XS[512 + sl]);
        short8 xl = __builtin_bit_cast(short8, XS[1024 + sl]);
        const int po = rr * TN + 16 * s + 8 * g;
        short8 ph = *(const short8*)&PTH[po];
        short8 pm = *(const short8*)&PTM[po];
        short8 pl = *(const short8*)&PTL[po];
        D1 = MFMA(xh, xh, D1);          // H H^T
        D1 = MFMA(xm, xm, D1);          // M M^T
        D2 = MFMA(xh, xm, D2);          // H M^T   (+ transpose at reduce)
        D3 = MFMA(xh, xl, D3);          // H L^T   (+ transpose at reduce)
        DQ = MFMA(xh, ph, DQ);
        DQ = MFMA(xh, pm, DQ);
        DQ = MFMA(xm, ph, DQ);
        DQ = MFMA(xh, pl, DQ);
        DQ = MFMA(xl, ph, DQ);
        DQ = MFMA(xm, pm, DQ);
    }

    // ---- cross-wave reduce (dump to LDS scratch, stride 20 words: conflict-free b128 writes) ----
    // C/D layout 32x32: col = lane&31, row = (reg&3) + 8*(reg>>2) + 4*(lane>>5)
    #define DUMP_REDUCE(D, dst)                                                            \
        __syncthreads();                                                                   \
        _Pragma("unroll")                                                                  \
        for (int i = 0; i < 4; ++i)                                                        \
            *(float4*)&dmp[tid * 20 + 4 * i] =                                             \
                make_float4((D)[4*i], (D)[4*i+1], (D)[4*i+2], (D)[4*i+3]);                 \
        __syncthreads();                                                                   \
        _Pragma("unroll")                                                                  \
        for (int it = 0; it < 4; ++it) {                                                   \
            const int e = tid + 256 * it;                                                  \
            const int r = e >> 5, co = e & 31;                                             \
            const int ln = co + 32 * ((r >> 2) & 1);                                       \
            const int rg = (r & 3) + 4 * (r >> 3);                                         \
            (dst)[e] = dmp[ln * 20 + rg] + dmp[(64 + ln) * 20 + rg]                        \
                     + dmp[(128 + ln) * 20 + rg] + dmp[(192 + ln) * 20 + rg];              \
        }

    DUMP_REDUCE(D1, Ssum)
    DUMP_REDUCE(D2, T2)
    DUMP_REDUCE(D3, T3)
    __syncthreads();
    {
        float* Sb = Sg + (size_t)b * 1024;
        #pragma unroll
        for (int it = 0; it < 4; ++it) {
            const int e = tid + 256 * it;
            const int r = e >> 5, co = e & 31;
            const int et = (co << 5) | r;
            atomicAdd(&Sb[e], Ssum[e] + T2[e] + T2[et] + T3[e] + T3[et]);
        }
    }
    // ---- Q reduce ----
    __syncthreads();
    #pragma unroll
    for (int i = 0; i < 4; ++i)
        *(float4*)&dmp[tid * 20 + 4 * i] = make_float4(DQ[4*i], DQ[4*i+1], DQ[4*i+2], DQ[4*i+3]);
    __syncthreads();
    if (tid < 96) {
        const int c2 = tid / 3, r2 = tid - 3 * c2;
        const int ln = r2 + 32 * ((c2 >> 2) & 1);
        const int rg = (c2 & 3) + 4 * (c2 >> 3);
        float s = dmp[ln * 20 + rg] + dmp[(64 + ln) * 20 + rg]
                + dmp[(128 + ln) * 20 + rg] + dmp[(192 + ln) * 20 + rg];
        atomicAdd(&Qg[(size_t)b * 96 + tid], s);
    }
}

// ---------------- k2: per-batch V = S*Q0, CholQR2 -> U (32x3, padded to 32x4) ----------------
__global__ __launch_bounds__(128)
void k2_solve(const float* __restrict__ Sg, const float* __restrict__ Qg,
              float* __restrict__ Uo)
{
    const int b = blockIdx.x, tid = threadIdx.x;
    __shared__ float S[1024];
    __shared__ float Qv[96];
    __shared__ float V[96];
    __shared__ float G[6], L[6];

    #pragma unroll
    for (int i = 0; i < 8; ++i) S[tid + 128 * i] = Sg[(size_t)b * 1024 + tid + 128 * i];
    if (tid < 96) Qv[tid] = Qg[(size_t)b * 96 + tid];
    __syncthreads();
    if (tid < 96) {
        const int c = tid / 3, r = tid % 3;
        float s = 0.f;
        #pragma unroll 8
        for (int cc = 0; cc < 32; ++cc) s += S[c * 32 + cc] * Qv[cc * 3 + r];
        V[tid] = s;
    }
    for (int round = 0; round < 2; ++round) {
        __syncthreads();
        if (tid < 6) {
            const int r = (tid > 2) ? 2 : ((tid > 0) ? 1 : 0);
            const int s = tid - (r * (r + 1)) / 2;
            float g = 0.f;
            for (int c = 0; c < 32; ++c) g += V[c * 3 + r] * V[c * 3 + s];
            G[tid] = g;
        }
        __syncthreads();
        if (tid == 0) {
            const float l00 = sqrtf(G[0]);
            const float l10 = G[1] / l00, l20 = G[3] / l00;
            const float l11 = sqrtf(G[2] - l10 * l10);
            const float l21 = (G[4] - l20 * l10) / l11;
            const float l22 = sqrtf(G[5] - l20 * l20 - l21 * l21);
            L[0] = l00; L[1] = l10; L[2] = l11; L[3] = l20; L[4] = l21; L[5] = l22;
        }
        __syncthreads();
        if (tid < 32) {
            const float v0 = V[tid * 3 + 0], v1 = V[tid * 3 + 1], v2 = V[tid * 3 + 2];
            const float u0 = v0 / L[0];
            const float u1 = (v1 - L[1] * u0) / L[2];
            const float u2 = (v2 - L[3] * u0 - L[4] * u1) / L[5];
            V[tid * 3 + 0] = u0; V[tid * 3 + 1] = u1; V[tid * 3 + 2] = u2;
        }
    }
    __syncthreads();
    if (tid < 32) {
        Uo[(size_t)b * 128 + tid * 4 + 0] = V[tid * 3 + 0];
        Uo[(size_t)b * 128 + tid * 4 + 1] = V[tid * 3 + 1];
        Uo[(size_t)b * 128 + tid * 4 + 2] = V[tid * 3 + 2];
        Uo[(size_t)b * 128 + tid * 4 + 3] = 0.f;
    }
}

// ---------------- k3: out = U * (U^T X), pure streaming ----------------
__global__ __launch_bounds__(256)
void k3_out(const float* __restrict__ x, const float* __restrict__ Uw,
            float* __restrict__ out)
{
    const int b = blockIdx.y, tid = threadIdx.x;
    __shared__ float Us[32][4];
    if (tid < 128) ((float*)Us)[tid] = Uw[(size_t)b * 128 + tid];
    __syncthreads();
    const int g = blockIdx.x * 256 + tid;
    if (g >= N_HW / 4) return;

    const float* Xb = x   + (size_t)b * 32 * N_HW + 4 * (size_t)g;
    float*       Ob = out + (size_t)b * 32 * N_HW + 4 * (size_t)g;

    float t0x = 0, t0y = 0, t0z = 0, t0w = 0;
    float t1x = 0, t1y = 0, t1z = 0, t1w = 0;
    float t2x = 0, t2y = 0, t2z = 0, t2w = 0;
    #pragma unroll 16
    for (int c = 0; c < 32; ++c) {
        float4 xv = *(const float4*)(Xb + (size_t)c * N_HW);
        const float u0 = Us[c][0], u1 = Us[c][1], u2 = Us[c][2];
        t0x += u0 * xv.x; t0y += u0 * xv.y; t0z += u0 * xv.z; t0w += u0 * xv.w;
        t1x += u1 * xv.x; t1y += u1 * xv.y; t1z += u1 * xv.z; t1w += u1 * xv.w;
        t2x += u2 * xv.x; t2y += u2 * xv.y; t2z += u2 * xv.z; t2w += u2 * xv.w;
    }
    #pragma unroll 16
    for (int c = 0; c < 32; ++c) {
        const float u0 = Us[c][0], u1 = Us[c][1], u2 = Us[c][2];
        f32x4 o;
        o.x = u0 * t0x + u1 * t1x + u2 * t2x;
        o.y = u0 * t0y + u1 * t1y + u2 * t2y;
        o.z = u0 * t0z + u1 * t1z + u2 * t2z;
        o.w = u0 * t0w + u1 * t1w + u2 * t2w;
        __builtin_nontemporal_store(o, (f32x4*)(Ob + (size_t)c * N_HW));
    }
}

extern "C" void kernel_launch(void* const* d_in, const int* in_sizes, int n_in,
                              void* d_out, int out_size, void* d_ws, size_t ws_size,
                              hipStream_t stream)
{
    const float* x = (const float*)d_in[0];
    const float* p = (const float*)d_in[1];
    float* ws = (float*)d_ws;
    float* Sg = ws;
    float* Qg = ws + WS_QG;
    float* U  = ws + WS_U;
    float* out = (float*)d_out;

    hipLaunchKernelGGL(k0_zero, dim3((ZTOT / 4 + 255) / 256), dim3(256), 0, stream, ws);
    hipLaunchKernelGGL(k1_gram, dim3(NCH, 64), dim3(256), 0, stream, x, p, Sg, Qg);
    hipLaunchKernelGGL(k2_solve, dim3(64), dim3(128), 0, stream, Sg, Qg, U);
    hipLaunchKernelGGL(k3_out, dim3((N_HW / 4 + 255) / 256, 64), dim3(256), 0, stream, x, U, out);
}